// Round 1
// baseline (591.885 us; speedup 1.0000x reference)
//
#include <hip/hip_runtime.h>

// CASSI forward: y[m, n+l] += x[m,n,l] * ca[m,n]
// x: (1, M, N, L) fp32, ca: (1, M, N, 1) fp32, y: (1, M, N+L-1, 1) fp32
//
// Strategy: one 256-thread block per row m. Per-row output accumulator
// (1087 floats) lives in LDS. Stream x coalesced as float4 (each float4 is
// within one n-row since L=64), fold ca at load, scatter with LDS fp32
// atomics (ds_add_f32; addresses within one wave-instruction are all
// distinct, max 2-way bank aliasing = free). Memory-bound: ~264 MiB total
// traffic -> ~42 us at 6.3 TB/s.

#define CASSI_M 1024
#define CASSI_N 1024
#define CASSI_L 64
#define CASSI_OUTW (CASSI_N + CASSI_L - 1)  // 1087

__global__ __launch_bounds__(256) void cassi_scatter_kernel(
    const float* __restrict__ x, const float* __restrict__ ca,
    float* __restrict__ out) {
    __shared__ float y_lds[CASSI_OUTW];

    const int m = blockIdx.x;
    const int tid = threadIdx.x;

    // zero the per-row accumulator
    for (int c = tid; c < CASSI_OUTW; c += 256) y_lds[c] = 0.0f;
    __syncthreads();

    const float* __restrict__ xrow = x + (size_t)m * (CASSI_N * CASSI_L);
    const float* __restrict__ carow = ca + (size_t)m * CASSI_N;

    // (N*L) floats per row / (256 threads * 4 floats) = 64 rounds
    constexpr int ROUNDS = (CASSI_N * CASSI_L) / (256 * 4);
#pragma unroll 4
    for (int r = 0; r < ROUNDS; ++r) {
        const int f = (r * 256 + tid) * 4;   // flat offset within the row
        const int n = f >> 6;                // f / L
        const int l = f & 63;                // f % L  (multiple of 4)
        const float4 v = *reinterpret_cast<const float4*>(xrow + f);
        const float cav = carow[n];
        const int base = n + l;              // destination column of element 0
        atomicAdd(&y_lds[base + 0], v.x * cav);
        atomicAdd(&y_lds[base + 1], v.y * cav);
        atomicAdd(&y_lds[base + 2], v.z * cav);
        atomicAdd(&y_lds[base + 3], v.w * cav);
    }
    __syncthreads();

    // coalesced writeback of the finished row
    float* __restrict__ orow = out + (size_t)m * CASSI_OUTW;
    for (int c = tid; c < CASSI_OUTW; c += 256) orow[c] = y_lds[c];
}

extern "C" void kernel_launch(void* const* d_in, const int* in_sizes, int n_in,
                              void* d_out, int out_size, void* d_ws, size_t ws_size,
                              hipStream_t stream) {
    const float* x  = (const float*)d_in[0];   // (1, M, N, L)
    const float* ca = (const float*)d_in[1];   // (1, M, N, 1)
    float* out = (float*)d_out;                // (1, M, N+L-1, 1)
    (void)in_sizes; (void)n_in; (void)out_size; (void)d_ws; (void)ws_size;

    cassi_scatter_kernel<<<CASSI_M, 256, 0, stream>>>(x, ca, out);
}

// Round 2
// 369.195 us; speedup vs baseline: 1.6032x; 1.6032x over previous
//
#include <hip/hip_runtime.h>

// CASSI forward: y[m, n+l] += x[m,n,l] * ca[m,n]
// x: (1, M, N, L) fp32, ca: (1, M, N, 1) fp32, y: (1, M, N+L-1, 1) fp32
//
// R1 post-mortem: LDS fp32 atomicAdd lowered to a CAS retry loop (serialized
// ~150+ cyc/element dependent chains + cross-wave retry storms) -> 338 us,
// VALUBusy 1%. R2: invert to a GATHER: y[o] = sum_l x[o-l][l]*ca[o-l].
// Stage 128-n chunks of x (ca folded) into LDS with padded stride P=65
// (gather across lanes strides 65 -> conflict-free), each thread owns 5
// output columns in registers. No atomics anywhere.

#define CASSI_M 1024
#define CASSI_N 1024
#define CASSI_L 64
#define CASSI_OUTW (CASSI_N + CASSI_L - 1)  // 1087

constexpr int CN = 128;              // n-chunk per LDS tile
constexpr int P = CASSI_L + 1;       // 65: padded LDS stride (floats)
constexpr int NCHUNK = CASSI_N / CN; // 8
constexpr int OPT = 5;               // output columns per thread (ceil(1087/256))

__global__ __launch_bounds__(256) void cassi_gather_kernel(
    const float* __restrict__ x, const float* __restrict__ ca,
    float* __restrict__ out) {
    __shared__ float xs[CN * P];     // 33,280 B -> 4 blocks/CU

    const int m = blockIdx.x;
    const int t = threadIdx.x;

    float acc[OPT];
#pragma unroll
    for (int j = 0; j < OPT; ++j) acc[j] = 0.0f;

    const float* __restrict__ xrow = x + (size_t)m * (CASSI_N * CASSI_L);
    const float* __restrict__ carow = ca + (size_t)m * CASSI_N;

    for (int c = 0; c < NCHUNK; ++c) {
        const int n0 = c * CN;

        // ---- stage chunk: CN*64 floats, ca folded at load ----
        // 8 float4 per thread; loads batched ahead of LDS writes for MLP.
#pragma unroll
        for (int s = 0; s < (CN * CASSI_L) / (256 * 4); ++s) {  // 8
            const int f = (s * 256 + t) * 4;   // flat offset within chunk
            const int nrel = f >> 6;           // f / 64
            const int l = f & 63;              // multiple of 4
            const float4 v = *reinterpret_cast<const float4*>(xrow + n0 * CASSI_L + f);
            const float cav = carow[n0 + nrel];
            float* dst = &xs[nrel * P + l];
            dst[0] = v.x * cav;
            dst[1] = v.y * cav;
            dst[2] = v.z * cav;
            dst[3] = v.w * cav;
        }
        __syncthreads();

        // ---- gather: thread t owns output columns o = t + 256*j ----
#pragma unroll
        for (int j = 0; j < OPT; ++j) {
            const int o = t + 256 * j;
            if (o < CASSI_OUTW) {
                int llo = o - (n0 + CN - 1); if (llo < 0) llo = 0;
                int lhi = o - n0;            if (lhi > 63) lhi = 63;
                if (llo == 0 && lhi == 63) {
                    // interior fast path: uniform full range, unrolled,
                    // 2 partial sums to break the dependent add chain
                    const int b = o - n0;   // n_rel for l=0
                    float s0 = 0.0f, s1 = 0.0f;
#pragma unroll
                    for (int l = 0; l < 64; l += 2) {
                        s0 += xs[(b - l) * P + l];
                        s1 += xs[(b - l - 1) * P + l + 1];
                    }
                    acc[j] += s0 + s1;
                } else {
                    for (int l = llo; l <= lhi; ++l)
                        acc[j] += xs[(o - n0 - l) * P + l];
                }
            }
        }
        __syncthreads();
    }

    // ---- coalesced writeback ----
    float* __restrict__ orow = out + (size_t)m * CASSI_OUTW;
#pragma unroll
    for (int j = 0; j < OPT; ++j) {
        const int o = t + 256 * j;
        if (o < CASSI_OUTW) orow[o] = acc[j];
    }
}

extern "C" void kernel_launch(void* const* d_in, const int* in_sizes, int n_in,
                              void* d_out, int out_size, void* d_ws, size_t ws_size,
                              hipStream_t stream) {
    const float* x  = (const float*)d_in[0];   // (1, M, N, L)
    const float* ca = (const float*)d_in[1];   // (1, M, N, 1)
    float* out = (float*)d_out;                // (1, M, N+L-1, 1)
    (void)in_sizes; (void)n_in; (void)out_size; (void)d_ws; (void)ws_size;

    cassi_gather_kernel<<<CASSI_M, 256, 0, stream>>>(x, ca, out);
}